// Round 5
// baseline (290.175 us; speedup 1.0000x reference)
//
#include <hip/hip_runtime.h>
#include <hip/hip_fp16.h>

#define BB 4
#define CC 3
#define HH 384
#define WW 384
#define HW (HH * WW)
#define NP 13        // planes: 0..11 = aff half-window, 12 = g = mask/sumz
#define NITER 20
#define PADF 2048    // guard floats around x buffers (max OOB reach is 772)
#define WGUARDH 2048 // guard halves before weight planes (backward reads reach -772)

static constexpr float INV_Z2 = 1.0f / (0.15f * 0.15f);

// Stored taps d=(dr,dc): dr>0 or (dr==0 && dc>0).
// plane idx: (0,1)->0 (0,2)->1 (1,-2..2)->2..6 (2,-2..2)->7..11.
// Symmetry: aff(p,p+d) == aff(p+d,p), so the "negative" half-window at p is
// A_d(p-d). Center tap aff(p,p)=1 exactly. Normalizer g=mask/sumz folds the
// mask (exact identity).

// ---------------------------------------------------------------------------
__global__ __launch_bounds__(256) void prep_sym(
    const float* __restrict__ img, const float* __restrict__ feat,
    const float* __restrict__ mask, __half* __restrict__ wgt,
    float* __restrict__ x0)
{
    int gid = blockIdx.x * 256 + threadIdx.x;
    int p0 = gid * 2;
    if (p0 >= BB * HW) return;
    int b   = p0 / HW;
    int rem = p0 - b * HW;          // even
    int h   = rem / WW;
    int wc  = rem - h * WW;

    const float* imgb = img + (size_t)b * CC * HW;
    const size_t bHW = (size_t)b * HW;

    float2 f  = *(const float2*)(feat + bHW + rem);
    float2 mk = *(const float2*)(mask + bHW + rem);
    *(float2*)(x0 + bHW + rem) = make_float2(f.x * mk.x, f.y * mk.y);

    float v0[2], v1[2], v2[2];
#pragma unroll
    for (int s = 0; s < 2; ++s) {
        v0[s] = imgb[0 * HW + rem + s] + 10.f;
        v1[s] = imgb[1 * HW + rem + s] + 10.f;
        v2[s] = imgb[2 * HW + rem + s] + 10.f;
    }

    float a[12][2];
    float sz[2] = {1.f + 1e-10f, 1.f + 1e-10f};   // center aff = exp(0) = 1
#pragma unroll
    for (int dr = -2; dr <= 2; ++dr) {
#pragma unroll
        for (int dc = -2; dc <= 2; ++dc) {
            if (dr == 0 && dc == 0) continue;
            int rr = h + dr;
#pragma unroll
            for (int s = 0; s < 2; ++s) {
                int cc2 = wc + s + dc;
                float av = 0.f;
                if (rr >= 0 && rr < HH && cc2 >= 0 && cc2 < WW) {
                    int q = rr * WW + cc2;
                    float d0 = imgb[0 * HW + q] + 10.f - v0[s];
                    float d1 = imgb[1 * HW + q] + 10.f - v1[s];
                    float d2 = imgb[2 * HW + q] + 10.f - v2[s];
                    av = __expf(-(d0 * d0 + d1 * d1 + d2 * d2) * INV_Z2);
                }
                sz[s] += av;
                if (dr > 0 || (dr == 0 && dc > 0)) {
                    int idx = (dr == 0) ? (dc - 1) : (2 + (dr - 1) * 5 + (dc + 2));
                    a[idx][s] = av;
                }
            }
        }
    }
#pragma unroll
    for (int t = 0; t < 12; ++t)
        *(__half2*)(wgt + ((size_t)b * NP + t) * HW + rem) =
            __floats2half2_rn(a[t][0], a[t][1]);
    *(__half2*)(wgt + ((size_t)b * NP + 12) * HW + rem) =
        __floats2half2_rn(mk.x / sz[0], mk.y / sz[1]);
}

// ---------------------------------------------------------------------------
// weight fetch helpers (4 px per thread, rem multiple of 4)
// ---------------------------------------------------------------------------
__device__ __forceinline__ void fwd_w(const __half* __restrict__ plane,
                                      int rem, float w[4])
{
    float2 v = *(const float2*)(plane + rem);      // 8B aligned
    const __half2* h2 = (const __half2*)&v;
    float2 x0 = __half22float2(h2[0]), x1 = __half22float2(h2[1]);
    w[0] = x0.x; w[1] = x0.y; w[2] = x1.x; w[3] = x1.y;
}

// 4 halves starting at (possibly misaligned) index q0; rem%4==0 and the tap
// offset is a compile-time constant, so s folds to a constant per call site.
__device__ __forceinline__ void bwd_w(const __half* __restrict__ plane,
                                      int q0, float w[4])
{
    int s = q0 & 3;
    int q0a = q0 - s;
    if (s == 0) {
        float2 v = *(const float2*)(plane + q0a);
        const __half2* h2 = (const __half2*)&v;
        float2 x0 = __half22float2(h2[0]), x1 = __half22float2(h2[1]);
        w[0] = x0.x; w[1] = x0.y; w[2] = x1.x; w[3] = x1.y;
    } else {
        union { float2 f[2]; __half hh[8]; } u;
        u.f[0] = *(const float2*)(plane + q0a);
        u.f[1] = *(const float2*)(plane + q0a + 4);
        w[0] = __half2float(u.hh[s + 0]);
        w[1] = __half2float(u.hh[s + 1]);
        w[2] = __half2float(u.hh[s + 2]);
        w[3] = __half2float(u.hh[s + 3]);
    }
}

#define LOADX(rr)                                                          \
    {                                                                      \
        const float* p = xb + rem + (rr) * WW - 4;                         \
        float4 a0 = *(const float4*)p;                                     \
        float4 a1 = *(const float4*)(p + 4);                               \
        float4 a2 = *(const float4*)(p + 8);                               \
        xs[0] = a0.x; xs[1] = a0.y; xs[2]  = a0.z; xs[3]  = a0.w;          \
        xs[4] = a1.x; xs[5] = a1.y; xs[6]  = a1.z; xs[7]  = a1.w;          \
        xs[8] = a2.x; xs[9] = a2.y; xs[10] = a2.z; xs[11] = a2.w;          \
    }

template <bool EDGE>
__device__ __forceinline__ void iter_body(
    const __half* __restrict__ wb, const float* __restrict__ xb,
    int rem, int h, int c0, float* __restrict__ outp)
{
    float acc[4] = {0.f, 0.f, 0.f, 0.f};
    float xs[12];

    // ---- x row h-2: backward taps of planes (2,dc) = 7..11 ----
    LOADX(-2)
#pragma unroll
    for (int dci = 0; dci < 5; ++dci) {
        const int dc = dci - 2;
        float w[4];
        bwd_w(wb + (size_t)(7 + dci) * HW, rem - 2 * WW - dc, w);
        if (EDGE) {
            bool rowOK = (h - 2) >= 0;
#pragma unroll
            for (int j = 0; j < 4; ++j) {
                int cb = c0 + j - dc;
                w[j] = (rowOK && cb >= 0 && cb < WW) ? w[j] : 0.f;
            }
        }
#pragma unroll
        for (int j = 0; j < 4; ++j)
            acc[j] = fmaf(w[j], xs[j - dc + 4], acc[j]);
    }

    // ---- x row h-1: backward taps of planes (1,dc) = 2..6 ----
    LOADX(-1)
#pragma unroll
    for (int dci = 0; dci < 5; ++dci) {
        const int dc = dci - 2;
        float w[4];
        bwd_w(wb + (size_t)(2 + dci) * HW, rem - WW - dc, w);
        if (EDGE) {
            bool rowOK = (h - 1) >= 0;
#pragma unroll
            for (int j = 0; j < 4; ++j) {
                int cb = c0 + j - dc;
                w[j] = (rowOK && cb >= 0 && cb < WW) ? w[j] : 0.f;
            }
        }
#pragma unroll
        for (int j = 0; j < 4; ++j)
            acc[j] = fmaf(w[j], xs[j - dc + 4], acc[j]);
    }

    // ---- x row h: center + fwd/bwd of planes (0,1),(0,2) ----
    LOADX(0)
#pragma unroll
    for (int j = 0; j < 4; ++j)        // center tap, weight exactly 1
        acc[j] += xs[j + 4];
#pragma unroll
    for (int t = 0; t < 2; ++t) {      // forward (0,1),(0,2)
        const int dc = t + 1;
        float w[4];
        fwd_w(wb + (size_t)t * HW, rem, w);
#pragma unroll
        for (int j = 0; j < 4; ++j)
            acc[j] = fmaf(w[j], xs[j + dc + 4], acc[j]);
    }
#pragma unroll
    for (int t = 0; t < 2; ++t) {      // backward (0,1),(0,2)
        const int dc = t + 1;
        float w[4];
        bwd_w(wb + (size_t)t * HW, rem - dc, w);
        if (EDGE) {
#pragma unroll
            for (int j = 0; j < 4; ++j) {
                int cb = c0 + j - dc;
                w[j] = (cb >= 0) ? w[j] : 0.f;
            }
        }
#pragma unroll
        for (int j = 0; j < 4; ++j)
            acc[j] = fmaf(w[j], xs[j - dc + 4], acc[j]);
    }

    // ---- x row h+1: forward taps of planes (1,dc) = 2..6 ----
    LOADX(1)
#pragma unroll
    for (int dci = 0; dci < 5; ++dci) {
        const int dc = dci - 2;
        float w[4];
        fwd_w(wb + (size_t)(2 + dci) * HW, rem, w);
#pragma unroll
        for (int j = 0; j < 4; ++j)
            acc[j] = fmaf(w[j], xs[j + dc + 4], acc[j]);
    }

    // ---- x row h+2: forward taps of planes (2,dc) = 7..11 ----
    LOADX(2)
#pragma unroll
    for (int dci = 0; dci < 5; ++dci) {
        const int dc = dci - 2;
        float w[4];
        fwd_w(wb + (size_t)(7 + dci) * HW, rem, w);
#pragma unroll
        for (int j = 0; j < 4; ++j)
            acc[j] = fmaf(w[j], xs[j + dc + 4], acc[j]);
    }

    // ---- normalizer g = mask/sumz ----
    float2 gv = *(const float2*)(wb + (size_t)12 * HW + rem);
    const __half2* gh = (const __half2*)&gv;
    float2 g0 = __half22float2(gh[0]), g1 = __half22float2(gh[1]);
    *(float4*)outp = make_float4(acc[0] * g0.x, acc[1] * g0.y,
                                 acc[2] * g1.x, acc[3] * g1.y);
}

__global__ __launch_bounds__(256) void iter_sym(
    const __half* __restrict__ wgt, const float* __restrict__ xin,
    float* __restrict__ xout)
{
    int gid = blockIdx.x * 256 + threadIdx.x;
    int p0 = gid * 4;                  // grid sized exactly
    int b   = p0 / HW;
    int rem = p0 - b * HW;             // multiple of 4
    int h   = rem / WW;
    int c0  = rem - h * WW;

    const __half* wb = wgt + (size_t)b * NP * HW;
    const float*  xb = xin + (size_t)b * HW;
    float* op = xout + (size_t)b * HW + rem;

    if (h >= 2 && c0 != 0 && c0 != 380)
        iter_body<false>(wb, xb, rem, h, c0, op);   // interior: branch-free
    else
        iter_body<true>(wb, xb, rem, h, c0, op);    // border: per-tap masks
}

extern "C" void kernel_launch(void* const* d_in, const int* in_sizes, int n_in,
                              void* d_out, int out_size, void* d_ws, size_t ws_size,
                              hipStream_t stream)
{
    const float* img  = (const float*)d_in[0];
    const float* feat = (const float*)d_in[1];
    const float* mask = (const float*)d_in[2];
    float* out = (float*)d_out;

    // ws: [guard | wgt: B*13*HW halves (~15.3 MB) | PADF | xa | PADF | xb | PADF]
    __half* wgt = (__half*)d_ws + WGUARDH;
    size_t wbytes = (size_t)BB * NP * HW * sizeof(__half);
    float* fbase = (float*)((char*)wgt + ((wbytes + 255) & ~(size_t)255));
    float* xa = fbase + PADF;
    float* xb = xa + (size_t)BB * HW + PADF;

    const int n = BB * HW;
    prep_sym<<<(n / 2 + 255) / 256, 256, 0, stream>>>(img, feat, mask, wgt, xa);

    const int iblocks = n / 4 / 256;   // 576, exact
    float* cur = xa;
    float* nxt = xb;
    for (int it = 0; it < NITER - 1; ++it) {
        iter_sym<<<iblocks, 256, 0, stream>>>(wgt, cur, nxt);
        float* t = cur; cur = nxt; nxt = t;
    }
    iter_sym<<<iblocks, 256, 0, stream>>>(wgt, cur, out);
}